// Round 15
// baseline (150.620 us; speedup 1.0000x reference)
//
#include <hip/hip_runtime.h>
#include <hip/hip_bf16.h>

// EdgeProbMLP: out[e] = sigmoid( relu( [x*y, x-y] @ W1.T + b1 ) @ W2.T + b2 )
// x = relu(nf[src] @ Wdim.T + bdim), y = same for dst.
// P[n] = relu(proj(nf[n])) precomputed once (f16, d_ws).
// R15 = R14 (W1 f16 strips in registers, async global_load_lds gather into
// double-buffered LDS, source-side chunk swizzle, f16 packed mul/sub ->
// mfma_f32_32x32x16_f16, 2-phase pipeline) with ONE change: GRID 512->1024.
// R14's occupancy (21%) was grid-limited, not resource-limited: LDS 34.8KB
// allows 4 blocks/CU (139KB/160KB), VGPR=80 allows more, but 512 blocks =
// exactly 2/CU — no third block existed to cover the per-tile vmcnt drain
// stall (~45% of tile time). 1024 blocks = 4/CU, 2x resident waves.
// Falsifier: occupancy ~42% but dur>=125us => gather-service pipe saturated
// -> counted-vmcnt 3-buffer pipeline or demand reduction next.

#define N_NODES 100000
#define N_EDGES 1000000
#define NT      31250     // 1M / 32 edges per tile
#define GRID    1024      // 4 blocks/CU * 256 CUs (LDS-bound residency)

typedef unsigned int u32;
typedef u32   u32x2 __attribute__((ext_vector_type(2)));
typedef u32   u32x4 __attribute__((ext_vector_type(4)));
typedef float f32x4 __attribute__((ext_vector_type(4)));
typedef float f32x16 __attribute__((ext_vector_type(16)));
typedef __bf16 bf16x8 __attribute__((ext_vector_type(8)));
typedef _Float16 f16x8 __attribute__((ext_vector_type(8)));

__device__ inline u32 pack2bf(float a, float b) {
    unsigned short ua = __builtin_bit_cast(unsigned short, (__bf16)a);
    unsigned short ub = __builtin_bit_cast(unsigned short, (__bf16)b);
    return (u32)ua | ((u32)ub << 16);
}
__device__ inline u32 pack2h(float a, float b) {
    unsigned short ua = __builtin_bit_cast(unsigned short, (_Float16)a);
    unsigned short ub = __builtin_bit_cast(unsigned short, (_Float16)b);
    return (u32)ua | ((u32)ub << 16);
}

// async gather: per-lane global src, HW writes LDS at (uniform base + lane*16)
__device__ __forceinline__ void gload16(const unsigned char* g, unsigned char* l) {
    __builtin_amdgcn_global_load_lds(
        (__attribute__((address_space(1))) unsigned int*)g,
        (__attribute__((address_space(3))) unsigned int*)l,
        16, 0, 0);
}

// ---------------------------------------------------------------------------
// Kernel 1: P[n][c] = relu(sum_k nf[n][k] * Wdim[c][k] + bdim[c]), F16 out.
// ---------------------------------------------------------------------------
__global__ __launch_bounds__(256, 1) void k_project(
    const float* __restrict__ nf, const float* __restrict__ Wdim,
    const float* __restrict__ bdim, unsigned short* __restrict__ P)
{
    __shared__ unsigned char lA[128 * 256];  // 32 KB: Wdim as bf16 [128ch][128k]
    const int t = threadIdx.x;
    for (int ci = t; ci < 2048; ci += 256) {
        const int row = ci >> 4;
        const int k8 = (ci & 15) << 3;
        const float* wp = Wdim + (row << 7) + k8;
        f32x4 v0 = *(const f32x4*)wp;
        f32x4 v1 = *(const f32x4*)(wp + 4);
        u32x4 pk = { pack2bf(v0[0], v0[1]), pack2bf(v0[2], v0[3]),
                     pack2bf(v1[0], v1[1]), pack2bf(v1[2], v1[3]) };
        int byte = (row << 8) + (k8 << 1);
        byte ^= (row & 15) << 4;
        *(u32x4*)(lA + byte) = pk;
    }
    __syncthreads();

    const int lane = t & 63;
    const int wave = t >> 6;
    const int cc = lane & 31;
    const int h  = lane >> 5;
    const int tile = blockIdx.x * 4 + wave;
    if (tile >= 3125) return;
    const int node = (tile << 5) + cc;
    const float* xrow = nf + ((size_t)node << 7);

    f32x4 rv[16];
#pragma unroll
    for (int kt = 0; kt < 8; ++kt) {
        const int kf = (kt << 4) + (h << 3);
        rv[2*kt]   = *(const f32x4*)(xrow + kf);
        rv[2*kt+1] = *(const f32x4*)(xrow + kf + 4);
    }

    f32x16 acc[4] = {};
#pragma unroll
    for (int kt = 0; kt < 8; ++kt) {
        const int kf = (kt << 4) + (h << 3);
        f32x4 v0 = rv[2*kt], v1 = rv[2*kt+1];
        bf16x8 bf;
        bf[0]=(__bf16)v0[0]; bf[1]=(__bf16)v0[1]; bf[2]=(__bf16)v0[2]; bf[3]=(__bf16)v0[3];
        bf[4]=(__bf16)v1[0]; bf[5]=(__bf16)v1[1]; bf[6]=(__bf16)v1[2]; bf[7]=(__bf16)v1[3];
        const int off = kf << 1;
#pragma unroll
        for (int t4 = 0; t4 < 4; ++t4) {
            const int arow = (t4 << 5) + cc;
            const int ab = ((arow << 8) + off) ^ ((arow & 15) << 4);
            bf16x8 af = __builtin_bit_cast(bf16x8, *(const u32x4*)(lA + ab));
            acc[t4] = __builtin_amdgcn_mfma_f32_32x32x16_bf16(af, bf, acc[t4], 0, 0, 0);
        }
    }
    unsigned short* prow = P + ((size_t)node << 7);
#pragma unroll
    for (int t4 = 0; t4 < 4; ++t4) {
#pragma unroll
        for (int q = 0; q < 4; ++q) {
            const int chb = (t4 << 5) + (q << 3) + (h << 2);
            f32x4 bb = *(const f32x4*)(bdim + chb);
            const float h0 = fmaxf(acc[t4][(q << 2) + 0] + bb[0], 0.f);
            const float h1 = fmaxf(acc[t4][(q << 2) + 1] + bb[1], 0.f);
            const float h2 = fmaxf(acc[t4][(q << 2) + 2] + bb[2], 0.f);
            const float h3 = fmaxf(acc[t4][(q << 2) + 3] + bb[3], 0.f);
            u32x2 st = { pack2h(h0, h1), pack2h(h2, h3) };   // F16 store
            *(u32x2*)(prow + chb) = st;
        }
    }
}

// ---------------------------------------------------------------------------
// Kernel 2: block-cooperative 32-edge tiles, f16 packed math.
// W1 strips (f16) in registers; edge rows async-gathered into dbuf'd LDS.
// Rows: r=0..31 src (x), r=32..63 dst (y); buf[r][c16] holds global chunk
// c ^ (r&15) (source-side swizzle). Wave w stages rows [w*16, w*16+16).
// ---------------------------------------------------------------------------
__global__ __launch_bounds__(256, 2) void k_edge(
    const unsigned short* __restrict__ P,
    const int* __restrict__ ei,          // [2][E] int32
    const float* __restrict__ W1, const float* __restrict__ b1,
    const float* __restrict__ W2, const float* __restrict__ b2,
    float* __restrict__ out)
{
    __shared__ unsigned char buf[2][64 * 256];   // 32 KB: 2 x 64 rows x 256B
    __shared__ float pr[2][4][32];               // per-wave partials (dbuf)
    __shared__ float sb1[128], sw2[128];
    const int t = threadIdx.x;
    const int lane = t & 63;
    const int wave = t >> 6;
    const int cc = lane & 31;     // edge column / A-row
    const int h  = lane >> 5;     // k-half
    if (t < 128) { sb1[t] = b1[t]; sw2[t] = W2[t]; }

    // ---- W1 strip -> f16 registers: wave w owns channels [w*32, w*32+32).
    f16x8 wf[16];
    {
        const float* wrow = W1 + (((wave << 5) + cc) << 8);   // 256 f32/row
#pragma unroll
        for (int kt = 0; kt < 8; ++kt) {
#pragma unroll
            for (int half = 0; half < 2; ++half) {
                const float* wp = wrow + (half << 7) + (kt << 4) + (h << 3);
                f32x4 a = *(const f32x4*)wp;
                f32x4 b = *(const f32x4*)(wp + 4);
                f16x8 f;
                f[0]=(_Float16)a[0]; f[1]=(_Float16)a[1]; f[2]=(_Float16)a[2]; f[3]=(_Float16)a[3];
                f[4]=(_Float16)b[0]; f[5]=(_Float16)b[1]; f[6]=(_Float16)b[2]; f[7]=(_Float16)b[3];
                wf[(kt << 1) + half] = f;
            }
        }
    }

    // lane-constant staging geometry: instr i covers rows w*16+i*4+(lane>>4),
    // slot chunk c = lane&15, global chunk = c ^ (r&15)
    const unsigned char* Pb = (const unsigned char*)P;
    const int* eb = ei + (wave < 2 ? 0 : N_EDGES - 32);   // dst waves offset
    int xo[4], rbase[4];
#pragma unroll
    for (int i = 0; i < 4; ++i) {
        const int rl = (i << 2) + (lane >> 4);            // r mod 16
        xo[i] = ((lane & 15) ^ (rl & 15)) << 4;
        rbase[i] = (wave << 4) + rl;                      // row within 0..63
    }
    const float b2v = b2[0];
    const int t0 = blockIdx.x;

    // ---- prologue: stage tile t0 into buf[0]; prefetch idx for t0+GRID
    int nidx0, nidx1, nidx2, nidx3;
    {
        int i0 = eb[(t0 << 5) + rbase[0]];
        int i1 = eb[(t0 << 5) + rbase[1]];
        int i2 = eb[(t0 << 5) + rbase[2]];
        int i3 = eb[(t0 << 5) + rbase[3]];
        gload16(Pb + ((size_t)i0 << 8) + xo[0], &buf[0][(rbase[0] & ~3) << 8]);
        gload16(Pb + ((size_t)i1 << 8) + xo[1], &buf[0][(rbase[1] & ~3) << 8]);
        gload16(Pb + ((size_t)i2 << 8) + xo[2], &buf[0][(rbase[2] & ~3) << 8]);
        gload16(Pb + ((size_t)i3 << 8) + xo[3], &buf[0][(rbase[3] & ~3) << 8]);
        int tn = t0 + GRID; tn = tn < NT ? tn : NT - 1;
        nidx0 = eb[(tn << 5) + rbase[0]];
        nidx1 = eb[(tn << 5) + rbase[1]];
        nidx2 = eb[(tn << 5) + rbase[2]];
        nidx3 = eb[(tn << 5) + rbase[3]];
    }
    __syncthreads();   // buf[0] staged (vmcnt drained), sb1/sw2 ready

    int p = 0;
    for (int tl = t0; tl < NT; tl += GRID) {
        // ---- STAGE next tile into buf[p^1] (async, zero VGPR payload)
        unsigned char* nb = buf[p ^ 1];
        gload16(Pb + ((size_t)nidx0 << 8) + xo[0], nb + ((rbase[0] & ~3) << 8));
        gload16(Pb + ((size_t)nidx1 << 8) + xo[1], nb + ((rbase[1] & ~3) << 8));
        gload16(Pb + ((size_t)nidx2 << 8) + xo[2], nb + ((rbase[2] & ~3) << 8));
        gload16(Pb + ((size_t)nidx3 << 8) + xo[3], nb + ((rbase[3] & ~3) << 8));
        // prefetch indices for tile tl + 2*GRID
        {
            int tn = tl + 2 * GRID; tn = tn < NT ? tn : NT - 1;
            nidx0 = eb[(tn << 5) + rbase[0]];
            nidx1 = eb[(tn << 5) + rbase[1]];
            nidx2 = eb[(tn << 5) + rbase[2]];
            nidx3 = eb[(tn << 5) + rbase[3]];
        }

        // ---- compute tile tl from buf[p]: f16 packed mul/sub -> f16 MFMA
        const unsigned char* bp_ = buf[p];
        const unsigned char* xb = bp_ + (cc << 8);            // src row cc
        const unsigned char* yb = bp_ + ((32 + cc) << 8);     // dst row cc
        const int cx = cc & 15;
        f32x16 acc = {};
#pragma unroll
        for (int kt = 0; kt < 8; ++kt) {
            const int co = (((kt << 1) + h) ^ cx) << 4;       // swizzled chunk
            const f16x8 xh = __builtin_bit_cast(f16x8, *(const u32x4*)(xb + co));
            const f16x8 yh = __builtin_bit_cast(f16x8, *(const u32x4*)(yb + co));
            const f16x8 bp = xh * yh;     // 4x v_pk_mul_f16
            const f16x8 bd = xh - yh;     // 4x v_pk_add_f16 (sub)
            acc = __builtin_amdgcn_mfma_f32_32x32x16_f16(wf[(kt << 1) + 0], bp, acc, 0, 0, 0);
            acc = __builtin_amdgcn_mfma_f32_32x32x16_f16(wf[(kt << 1) + 1], bd, acc, 0, 0, 0);
        }

        // ---- epilogue: relu(+b1).W2 for this wave's 32-channel strip
        float partial = 0.f;
#pragma unroll
        for (int q = 0; q < 4; ++q) {
            const int chb = (wave << 5) + (q << 3) + (h << 2);
            const f32x4 bb = *(const f32x4*)(sb1 + chb);
            const f32x4 ww = *(const f32x4*)(sw2 + chb);
#pragma unroll
            for (int rr = 0; rr < 4; ++rr) {
                const float hv = fmaxf(acc[(q << 2) + rr] + bb[rr], 0.f);
                partial += hv * ww[rr];
            }
        }
        partial += __shfl_xor(partial, 32);       // sum the two k-halves
        if (h == 0) pr[p][wave][cc] = partial;

        __syncthreads();   // pr[p] visible; buf[p^1] staged (vmcnt drained)

        if (t < 32) {      // wave 0, lanes 0..31: finish + store tile tl
            const float z = pr[p][0][t] + pr[p][1][t] + pr[p][2][t] + pr[p][3][t] + b2v;
            out[(tl << 5) + t] = 1.0f / (1.0f + __expf(-z));
        }
        p ^= 1;
    }
}

extern "C" void kernel_launch(void* const* d_in, const int* in_sizes, int n_in,
                              void* d_out, int out_size, void* d_ws, size_t ws_size,
                              hipStream_t stream) {
    const float* nf   = (const float*)d_in[0];
    const int*   ei   = (const int*)d_in[1];
    const float* Wdim = (const float*)d_in[2];
    const float* bdim = (const float*)d_in[3];
    const float* W1   = (const float*)d_in[4];
    const float* b1   = (const float*)d_in[5];
    const float* W2   = (const float*)d_in[6];
    const float* b2   = (const float*)d_in[7];
    float* out = (float*)d_out;
    unsigned short* P = (unsigned short*)d_ws;        // 100000*128 f16 = 25.6 MB

    k_project<<<dim3(782), dim3(256), 0, stream>>>(nf, Wdim, bdim, P);
    k_edge<<<dim3(GRID), dim3(256), 0, stream>>>(P, ei, W1, b1, W2, b2, out);
}

// Round 16
// 131.993 us; speedup vs baseline: 1.1411x; 1.1411x over previous
//
#include <hip/hip_runtime.h>
#include <hip/hip_bf16.h>

// EdgeProbMLP: out[e] = sigmoid( relu( [x*y, x-y] @ W1.T + b1 ) @ W2.T + b2 )
// x = relu(nf[src] @ Wdim.T + bdim), y = same for dst.
// P[n] = relu(proj(nf[n])) precomputed once (f16, d_ws).
// R16: 3-buffer counted-vmcnt pipeline. R15 showed more waves don't help ->
// the per-tile serial gather tail is the limiter: the 2-buffer loop's
// __syncthreads drains vmcnt(0), giving each stage only the ~1.3k-cy compute
// phase in flight. Now: 3 static LDS buffers (b0/b1/b2, compile-time names);
// raw s_barrier (asm, memory clobber) with NO vmcnt drain in the loop; each
// tile staged TWO steps before compute -> in-flight window = 1-2 full tiles.
// In-order vmcnt retirement: the compiler's own wait for last step's nidx
// consumption retires last step's stage loads - counted-wait semantics for
// free. One barrier/step; store of tile t happens at step t+1 (pr dbuf'd).
// LDS 3x16KB+tables ~51KB -> up to 3 blocks/CU, GRID=768.

#define N_NODES 100000
#define N_EDGES 1000000
#define NT      31250     // 1M / 32 edges per tile
#define GRID    768       // up to 3 blocks/CU

typedef unsigned int u32;
typedef u32   u32x2 __attribute__((ext_vector_type(2)));
typedef u32   u32x4 __attribute__((ext_vector_type(4)));
typedef float f32x4 __attribute__((ext_vector_type(4)));
typedef float f32x16 __attribute__((ext_vector_type(16)));
typedef __bf16 bf16x8 __attribute__((ext_vector_type(8)));
typedef _Float16 f16x8 __attribute__((ext_vector_type(8)));

__device__ inline u32 pack2bf(float a, float b) {
    unsigned short ua = __builtin_bit_cast(unsigned short, (__bf16)a);
    unsigned short ub = __builtin_bit_cast(unsigned short, (__bf16)b);
    return (u32)ua | ((u32)ub << 16);
}
__device__ inline u32 pack2h(float a, float b) {
    unsigned short ua = __builtin_bit_cast(unsigned short, (_Float16)a);
    unsigned short ub = __builtin_bit_cast(unsigned short, (_Float16)b);
    return (u32)ua | ((u32)ub << 16);
}

// async gather: per-lane global src, HW writes LDS at (uniform base + lane*16)
__device__ __forceinline__ void gload16(const unsigned char* g, unsigned char* l) {
    __builtin_amdgcn_global_load_lds(
        (__attribute__((address_space(1))) unsigned int*)g,
        (__attribute__((address_space(3))) unsigned int*)l,
        16, 0, 0);
}

// ---------------------------------------------------------------------------
// Kernel 1: P[n][c] = relu(sum_k nf[n][k] * Wdim[c][k] + bdim[c]), F16 out.
// ---------------------------------------------------------------------------
__global__ __launch_bounds__(256, 1) void k_project(
    const float* __restrict__ nf, const float* __restrict__ Wdim,
    const float* __restrict__ bdim, unsigned short* __restrict__ P)
{
    __shared__ unsigned char lA[128 * 256];  // 32 KB: Wdim as bf16 [128ch][128k]
    const int t = threadIdx.x;
    for (int ci = t; ci < 2048; ci += 256) {
        const int row = ci >> 4;
        const int k8 = (ci & 15) << 3;
        const float* wp = Wdim + (row << 7) + k8;
        f32x4 v0 = *(const f32x4*)wp;
        f32x4 v1 = *(const f32x4*)(wp + 4);
        u32x4 pk = { pack2bf(v0[0], v0[1]), pack2bf(v0[2], v0[3]),
                     pack2bf(v1[0], v1[1]), pack2bf(v1[2], v1[3]) };
        int byte = (row << 8) + (k8 << 1);
        byte ^= (row & 15) << 4;
        *(u32x4*)(lA + byte) = pk;
    }
    __syncthreads();

    const int lane = t & 63;
    const int wave = t >> 6;
    const int cc = lane & 31;
    const int h  = lane >> 5;
    const int tile = blockIdx.x * 4 + wave;
    if (tile >= 3125) return;
    const int node = (tile << 5) + cc;
    const float* xrow = nf + ((size_t)node << 7);

    f32x4 rv[16];
#pragma unroll
    for (int kt = 0; kt < 8; ++kt) {
        const int kf = (kt << 4) + (h << 3);
        rv[2*kt]   = *(const f32x4*)(xrow + kf);
        rv[2*kt+1] = *(const f32x4*)(xrow + kf + 4);
    }

    f32x16 acc[4] = {};
#pragma unroll
    for (int kt = 0; kt < 8; ++kt) {
        const int kf = (kt << 4) + (h << 3);
        f32x4 v0 = rv[2*kt], v1 = rv[2*kt+1];
        bf16x8 bf;
        bf[0]=(__bf16)v0[0]; bf[1]=(__bf16)v0[1]; bf[2]=(__bf16)v0[2]; bf[3]=(__bf16)v0[3];
        bf[4]=(__bf16)v1[0]; bf[5]=(__bf16)v1[1]; bf[6]=(__bf16)v1[2]; bf[7]=(__bf16)v1[3];
        const int off = kf << 1;
#pragma unroll
        for (int t4 = 0; t4 < 4; ++t4) {
            const int arow = (t4 << 5) + cc;
            const int ab = ((arow << 8) + off) ^ ((arow & 15) << 4);
            bf16x8 af = __builtin_bit_cast(bf16x8, *(const u32x4*)(lA + ab));
            acc[t4] = __builtin_amdgcn_mfma_f32_32x32x16_bf16(af, bf, acc[t4], 0, 0, 0);
        }
    }
    unsigned short* prow = P + ((size_t)node << 7);
#pragma unroll
    for (int t4 = 0; t4 < 4; ++t4) {
#pragma unroll
        for (int q = 0; q < 4; ++q) {
            const int chb = (t4 << 5) + (q << 3) + (h << 2);
            f32x4 bb = *(const f32x4*)(bdim + chb);
            const float h0 = fmaxf(acc[t4][(q << 2) + 0] + bb[0], 0.f);
            const float h1 = fmaxf(acc[t4][(q << 2) + 1] + bb[1], 0.f);
            const float h2 = fmaxf(acc[t4][(q << 2) + 2] + bb[2], 0.f);
            const float h3 = fmaxf(acc[t4][(q << 2) + 3] + bb[3], 0.f);
            u32x2 st = { pack2h(h0, h1), pack2h(h2, h3) };   // F16 store
            *(u32x2*)(prow + chb) = st;
        }
    }
}

// ---------------------------------------------------------------------------
// Kernel 2: block-cooperative 32-edge tiles, f16 packed math, 3-buffer
// counted-vmcnt pipeline. W1 strips (f16) in registers; rows async-gathered.
// Rows: r=0..31 src (x), r=32..63 dst (y); buf[r][c16] holds global chunk
// c ^ (r&15) (source-side swizzle). Wave w stages rows [w*16, w*16+16).
// ---------------------------------------------------------------------------
__global__ __launch_bounds__(256, 2) void k_edge(
    const unsigned short* __restrict__ P,
    const int* __restrict__ ei,          // [2][E] int32
    const float* __restrict__ W1, const float* __restrict__ B1,
    const float* __restrict__ W2, const float* __restrict__ B2,
    float* __restrict__ out)
{
    __shared__ unsigned char b0[64 * 256];   // 16 KB each, static names so
    __shared__ unsigned char b1[64 * 256];   // alias analysis + vmcnt counting
    __shared__ unsigned char b2[64 * 256];   // stay compile-time
    __shared__ float pr[2][4][32];           // per-wave partials (phase dbuf)
    __shared__ float sb1[128], sw2[128];
    const int t = threadIdx.x;
    const int lane = t & 63;
    const int wave = t >> 6;
    const int cc = lane & 31;     // edge column / A-row
    const int h  = lane >> 5;     // k-half
    if (t < 128) { sb1[t] = B1[t]; sw2[t] = W2[t]; }

    // ---- W1 strip -> f16 registers: wave w owns channels [w*32, w*32+32).
    f16x8 wf[16];
    {
        const float* wrow = W1 + (((wave << 5) + cc) << 8);   // 256 f32/row
#pragma unroll
        for (int kt = 0; kt < 8; ++kt) {
#pragma unroll
            for (int half = 0; half < 2; ++half) {
                const float* wp = wrow + (half << 7) + (kt << 4) + (h << 3);
                f32x4 a = *(const f32x4*)wp;
                f32x4 b = *(const f32x4*)(wp + 4);
                f16x8 f;
                f[0]=(_Float16)a[0]; f[1]=(_Float16)a[1]; f[2]=(_Float16)a[2]; f[3]=(_Float16)a[3];
                f[4]=(_Float16)b[0]; f[5]=(_Float16)b[1]; f[6]=(_Float16)b[2]; f[7]=(_Float16)b[3];
                wf[(kt << 1) + half] = f;
            }
        }
    }

    // staging geometry: instr i covers rows wave*16+i*4+(lane>>4);
    // slot chunk c = lane&15, global chunk = c ^ (r&15)
    const unsigned char* Pb = (const unsigned char*)P;
    const int* eb = ei + (wave < 2 ? 0 : N_EDGES - 32);   // dst waves offset
    const int rl = lane >> 4;
    const int rb0 = (wave << 4) + 0  + rl, rb1 = (wave << 4) + 4  + rl;
    const int rb2 = (wave << 4) + 8  + rl, rb3 = (wave << 4) + 12 + rl;
    const int xo0 = ((lane & 15) ^ (rb0 & 15)) << 4;
    const int xo1 = ((lane & 15) ^ (rb1 & 15)) << 4;
    const int xo2 = ((lane & 15) ^ (rb2 & 15)) << 4;
    const int xo3 = ((lane & 15) ^ (rb3 & 15)) << 4;
    const int lbo0 = (rb0 & ~3) << 8, lbo1 = (rb1 & ~3) << 8;
    const int lbo2 = (rb2 & ~3) << 8, lbo3 = (rb3 & ~3) << 8;
    const int cx = cc & 15;
    const float b2v = B2[0];
    const int t0 = blockIdx.x;

    int tl = t0, prev = -1, ph = 0;
    int nidx0, nidx1, nidx2, nidx3;

    // ---- prologue: stage T0->b0, T1->b1; load nidx for T2; one full drain.
    {
        const int* e0 = eb + (t0 << 5);
        int i0 = e0[rb0], i1 = e0[rb1], i2 = e0[rb2], i3 = e0[rb3];
        gload16(Pb + ((size_t)i0 << 8) + xo0, b0 + lbo0);
        gload16(Pb + ((size_t)i1 << 8) + xo1, b0 + lbo1);
        gload16(Pb + ((size_t)i2 << 8) + xo2, b0 + lbo2);
        gload16(Pb + ((size_t)i3 << 8) + xo3, b0 + lbo3);
    }
    {
        int tn = t0 + GRID; tn = tn < NT ? tn : NT - 1;
        const int* e1 = eb + (tn << 5);
        int i0 = e1[rb0], i1 = e1[rb1], i2 = e1[rb2], i3 = e1[rb3];
        gload16(Pb + ((size_t)i0 << 8) + xo0, b1 + lbo0);
        gload16(Pb + ((size_t)i1 << 8) + xo1, b1 + lbo1);
        gload16(Pb + ((size_t)i2 << 8) + xo2, b1 + lbo2);
        gload16(Pb + ((size_t)i3 << 8) + xo3, b1 + lbo3);
    }
    {
        int tn = t0 + 2 * GRID; tn = tn < NT ? tn : NT - 1;
        const int* e2 = eb + (tn << 5);
        nidx0 = e2[rb0]; nidx1 = e2[rb1]; nidx2 = e2[rb2]; nidx3 = e2[rb3];
    }
    __syncthreads();   // prologue drain: b0,b1 staged, tables ready

// One step: barrier (no vmcnt drain) -> store prev tile -> stage tl+2*GRID
// into BS (consumes nidx => compiler wait retires LAST step's loads — the
// counted-wait) -> load nidx for tl+3*GRID -> compute tl from BC -> partials.
#define STEP(BC, BS)                                                          \
    {                                                                         \
        asm volatile("s_waitcnt vmcnt(8)\n\ts_barrier" ::: "memory");         \
        if (prev >= 0 && t < 32) {                                            \
            const int pp = ph ^ 1;                                            \
            const float z = pr[pp][0][t] + pr[pp][1][t] + pr[pp][2][t]        \
                          + pr[pp][3][t] + b2v;                               \
            out[(prev << 5) + t] = 1.0f / (1.0f + __expf(-z));                \
        }                                                                     \
        gload16(Pb + ((size_t)nidx0 << 8) + xo0, (BS) + lbo0);                \
        gload16(Pb + ((size_t)nidx1 << 8) + xo1, (BS) + lbo1);                \
        gload16(Pb + ((size_t)nidx2 << 8) + xo2, (BS) + lbo2);                \
        gload16(Pb + ((size_t)nidx3 << 8) + xo3, (BS) + lbo3);                \
        {   int tn = tl + 3 * GRID; tn = tn < NT ? tn : NT - 1;               \
            const int* ebn = eb + (tn << 5);                                  \
            nidx0 = ebn[rb0]; nidx1 = ebn[rb1];                               \
            nidx2 = ebn[rb2]; nidx3 = ebn[rb3]; }                             \
        const unsigned char* xb = (BC) + (cc << 8);                           \
        const unsigned char* yb = (BC) + ((32 + cc) << 8);                    \
        f32x16 acc = {};                                                      \
        _Pragma("unroll")                                                     \
        for (int kt = 0; kt < 8; ++kt) {                                      \
            const int co = (((kt << 1) + h) ^ cx) << 4;                       \
            const f16x8 xh = __builtin_bit_cast(f16x8, *(const u32x4*)(xb + co)); \
            const f16x8 yh = __builtin_bit_cast(f16x8, *(const u32x4*)(yb + co)); \
            const f16x8 bpv = xh * yh;                                        \
            const f16x8 bdv = xh - yh;                                        \
            acc = __builtin_amdgcn_mfma_f32_32x32x16_f16(wf[(kt << 1) + 0], bpv, acc, 0, 0, 0); \
            acc = __builtin_amdgcn_mfma_f32_32x32x16_f16(wf[(kt << 1) + 1], bdv, acc, 0, 0, 0); \
        }                                                                     \
        float partial = 0.f;                                                  \
        _Pragma("unroll")                                                     \
        for (int q = 0; q < 4; ++q) {                                         \
            const int chb = (wave << 5) + (q << 3) + (h << 2);                \
            const f32x4 bb = *(const f32x4*)(sb1 + chb);                      \
            const f32x4 ww = *(const f32x4*)(sw2 + chb);                      \
            _Pragma("unroll")                                                 \
            for (int rr = 0; rr < 4; ++rr) {                                  \
                const float hv = fmaxf(acc[(q << 2) + rr] + bb[rr], 0.f);     \
                partial += hv * ww[rr];                                       \
            }                                                                 \
        }                                                                     \
        partial += __shfl_xor(partial, 32);                                   \
        if (h == 0) pr[ph][wave][cc] = partial;                               \
        asm volatile("s_waitcnt lgkmcnt(0)" ::: "memory");                    \
        prev = tl; tl += GRID; ph ^= 1;                                       \
    }

    while (tl < NT) {
        STEP(b0, b2);
        if (tl >= NT) break;
        STEP(b1, b0);
        if (tl >= NT) break;
        STEP(b2, b1);
    }
#undef STEP

    // ---- epilogue: store the last computed tile's output
    asm volatile("s_barrier" ::: "memory");
    if (prev >= 0 && t < 32) {
        const int pp = ph ^ 1;
        const float z = pr[pp][0][t] + pr[pp][1][t] + pr[pp][2][t]
                      + pr[pp][3][t] + b2v;
        out[(prev << 5) + t] = 1.0f / (1.0f + __expf(-z));
    }
}

extern "C" void kernel_launch(void* const* d_in, const int* in_sizes, int n_in,
                              void* d_out, int out_size, void* d_ws, size_t ws_size,
                              hipStream_t stream) {
    const float* nf   = (const float*)d_in[0];
    const int*   ei   = (const int*)d_in[1];
    const float* Wdim = (const float*)d_in[2];
    const float* bdim = (const float*)d_in[3];
    const float* W1   = (const float*)d_in[4];
    const float* b1   = (const float*)d_in[5];
    const float* W2   = (const float*)d_in[6];
    const float* b2   = (const float*)d_in[7];
    float* out = (float*)d_out;
    unsigned short* P = (unsigned short*)d_ws;        // 100000*128 f16 = 25.6 MB

    k_project<<<dim3(782), dim3(256), 0, stream>>>(nf, Wdim, bdim, P);
    k_edge<<<dim3(GRID), dim3(256), 0, stream>>>(P, ei, W1, b1, W2, b2, out);
}